// Round 2
// baseline (342.800 us; speedup 1.0000x reference)
//
#include <hip/hip_runtime.h>
#include <hip/hip_bf16.h>
#include <stdint.h>

#define B_    2
#define S_    2048
#define DIM_  2048
#define H_    16
#define NOPE_ 96
#define ROPE_ 32
#define HD_   128
#define KVR_  512
#define QR_   1536
#define BS_   (B_*S_)   // 4096
#define NQT_  (S_/128)  // 16 q-tiles per (b,h)

typedef __bf16 bf16_t;
typedef bf16_t bf16x8 __attribute__((ext_vector_type(8)));
typedef float  f32x4  __attribute__((ext_vector_type(4)));

__device__ __forceinline__ uint16_t f2bf(float f) {
  union { float f; uint32_t u; } v; v.f = f;
  uint32_t r = (v.u + 0x7fffu + ((v.u >> 16) & 1u)) >> 16;
  return (uint16_t)r;
}
// pack two f32 -> two bf16 (RNE), low = a, high = b
__device__ __forceinline__ uint32_t pk_bf16(float a, float b) {
  union { float f; uint32_t u; } x, y; x.f = a; y.f = b;
  uint32_t lo = (x.u + 0x7fffu + ((x.u >> 16) & 1u)) >> 16;
  uint32_t hi = (y.u + 0x7fffu + ((y.u >> 16) & 1u)) & 0xffff0000u;
  return hi | lo;
}

// async global->LDS, 16B per lane; LDS dest is wave-uniform base + lane*16
__device__ __forceinline__ void gl_lds16(const void* g, void* l) {
  __builtin_amdgcn_global_load_lds(
      (const __attribute__((address_space(1))) uint32_t*)g,
      (__attribute__((address_space(3))) uint32_t*)l, 16, 0, 0);
}

// ---------------- prep megakernel: cast x + all weight transposes ----------------
__device__ __forceinline__ void transpose_tile(const float* __restrict__ W,
                                               uint16_t* __restrict__ Wt,
                                               int K, int N, float scale, int lbid,
                                               float (*tile)[65]) {
  const int nb = N / 64;
  const int n0 = (lbid % nb) * 64, k0 = (lbid / nb) * 64;
  const int tid = threadIdx.x;
  #pragma unroll
  for (int i = 0; i < 4; i++) {
    int p = i * 256 + tid;
    int r = p >> 4, c4 = (p & 15) * 4;
    float4 v = *(const float4*)&W[(size_t)(k0 + r) * N + n0 + c4];
    tile[r][c4 + 0] = v.x; tile[r][c4 + 1] = v.y; tile[r][c4 + 2] = v.z; tile[r][c4 + 3] = v.w;
  }
  __syncthreads();
  #pragma unroll
  for (int i = 0; i < 4; i++) {
    int p = i * 256 + tid;
    int rn = p >> 4, c4 = (p & 15) * 4;
    ushort4 o;
    o.x = f2bf(tile[c4 + 0][rn] * scale); o.y = f2bf(tile[c4 + 1][rn] * scale);
    o.z = f2bf(tile[c4 + 2][rn] * scale); o.w = f2bf(tile[c4 + 3][rn] * scale);
    *(ushort4*)&Wt[(size_t)(n0 + rn) * K + k0 + c4] = o;
  }
}

#define CAST_BLKS 2048   // 8.4M elems / 4096
__global__ __launch_bounds__(256) void prep_k(
    const float* __restrict__ x,
    const float* __restrict__ wqd, const float* __restrict__ wqu,
    const float* __restrict__ wkvd, const float* __restrict__ wn,
    const float* __restrict__ wr, const float* __restrict__ wv,
    const float* __restrict__ wo,
    uint16_t* __restrict__ xb, uint16_t* __restrict__ wdT,
    uint16_t* __restrict__ wquT, uint16_t* __restrict__ wkrT,
    uint16_t* __restrict__ wvT, uint16_t* __restrict__ woT, float qscale) {
  __shared__ __align__(16) float tile[64][65];
  int bid = blockIdx.x;
  const int tid = threadIdx.x;
  if (bid < CAST_BLKS) {
    #pragma unroll
    for (int p = 0; p < 4; p++) {
      int i = bid * 4096 + p * 1024 + tid * 4;
      float4 v = *(const float4*)&x[i];
      ushort4 o; o.x = f2bf(v.x); o.y = f2bf(v.y); o.z = f2bf(v.z); o.w = f2bf(v.w);
      *(ushort4*)&xb[i] = o;
    }
    return;
  }
  bid -= CAST_BLKS;
  if (bid < 768)               transpose_tile(wqd,  wdT,                        2048, 1536, 1.f,    bid, tile);
  else if ((bid -= 768) < 256) transpose_tile(wkvd, wdT + (size_t)QR_ * DIM_,   2048,  512, 1.f,    bid, tile);
  else if ((bid -= 256) < 768) transpose_tile(wqu,  wquT,                       1536, 2048, qscale, bid, tile);
  else if ((bid -= 768) < 192) transpose_tile(wn,   wkrT,                        512, 1536, 1.f,    bid, tile);
  else if ((bid -= 192) < 64)  transpose_tile(wr,   wkrT + (size_t)1536 * 512,   512,  512, 1.f,    bid, tile);
  else if ((bid -= 64) < 256)  transpose_tile(wv,   wvT,                         512, 2048, 1.f,    bid, tile);
  else                         transpose_tile(wo,   woT, 2048, 2048, 1.f, bid - 256, tile);
}
#define PREP_BLKS (CAST_BLKS + 768 + 256 + 768 + 192 + 64 + 256 + 1024)

// ---------------- GEMM v2: C(MxN) = A(MxK,bf16) * Bt(NxK,bf16)^T ----------------
// 256x128 tile, BK=64, 8 waves (4M x 2N, 64x64 per wave), triple-buffered LDS (144 KB),
// counted vmcnt(6) pipeline (never drains in main loop), ONE raw s_barrier per K-tile,
// s_setprio around MFMA clusters.
// MODE 0: bf16; 1: f32; 2: q_up + RoPE (d>=96); 3: k_up + nope/rope scatter.
template<int MODE>
__device__ __forceinline__ void gemm_body2(const uint16_t* __restrict__ A,
                                           const uint16_t* __restrict__ Bt,
                                           void* __restrict__ C,
                                           int bx, int by, int K,
                                           int lda, int ldb, int ldc,
                                           const float* __restrict__ cos_t,
                                           const float* __restrict__ sin_t,
                                           uint16_t (*lds)[64]) {
  const int tid = threadIdx.x;
  const int wave = tid >> 6, lane = tid & 63;
  const int wm = wave & 3, wn = wave >> 2;      // 4M x 2N
  const int m0 = by * 256, n0 = bx * 128;
  const int fr = lane & 15, fq = lane >> 4;

  const int srow = lane >> 3;                   // 0..7
  const int sch  = (lane & 7) ^ (srow & 7);     // pre-swizzled k-chunk

  // per-lane global staging bases (swizzled chunk baked in)
  const uint16_t* Ag = A  + (size_t)(m0 + wave * 32 + srow) * lda + sch * 8;
  const uint16_t* Bg = Bt + (size_t)(n0 + wave * 16 + srow) * ldb + sch * 8;
  const int NT = K >> 6;

  // stage whole K-tile t into buffer b (6 gl_lds per wave: 4 A rounds + 2 B rounds)
  auto stage_all = [&](int t, int b) {
    uint16_t (*bufA)[64] = lds + b * 384;
    uint16_t (*bufB)[64] = lds + b * 384 + 256;
    const uint16_t* ag = Ag + (size_t)t * 64;
    const uint16_t* bg = Bg + (size_t)t * 64;
    #pragma unroll
    for (int i = 0; i < 4; i++)
      gl_lds16(ag + (size_t)(i * 8) * lda, &bufA[wave * 32 + i * 8][0]);
    #pragma unroll
    for (int i = 0; i < 2; i++)
      gl_lds16(bg + (size_t)(i * 8) * ldb, &bufB[wave * 16 + i * 8][0]);
  };

  f32x4 acc[4][4] = {};
  stage_all(0, 0);   // prologue: tiles 0 and 1 in flight (12 loads/wave)
  stage_all(1, 1);

  int cb = 0;        // compute buffer = t % 3
  for (int t = 0; t < NT; ++t) {
    const bool pre = (t + 2 < NT);
    const int sb = (cb >= 1) ? cb - 1 : 2;      // (cb+2)%3 — stage buffer
    uint16_t (*bufA)[64] = lds + cb * 384;
    uint16_t (*bufB)[64] = lds + cb * 384 + 256;
    uint16_t (*sA)[64]   = lds + sb * 384;
    uint16_t (*sB)[64]   = lds + sb * 384 + 256;
    const uint16_t* ag = Ag + (size_t)(t + 2) * 64;
    const uint16_t* bg = Bg + (size_t)(t + 2) * 64;

    // tile t landed (6 newest = tile t+1 stay in flight); all waves' stores visible
    if (t == NT - 1) { asm volatile("s_waitcnt vmcnt(0)" ::: "memory"); }
    else             { asm volatile("s_waitcnt vmcnt(6)" ::: "memory"); }
    __builtin_amdgcn_s_barrier();
    asm volatile("" ::: "memory");   // fence: no LDS reads hoist above the barrier

    // B fragments for the whole tile (shared across the 4 m-phases)
    bf16x8 bfr[4][2];
    #pragma unroll
    for (int nt = 0; nt < 4; nt++)
      #pragma unroll
      for (int ks = 0; ks < 2; ks++)
        bfr[nt][ks] = *(const bf16x8*)&bufB[wn * 64 + nt * 16 + fr]
                                          [((ks * 4 + fq) ^ (fr & 7)) * 8];

    #pragma unroll
    for (int p = 0; p < 4; p++) {
      bf16x8 afr[2];
      #pragma unroll
      for (int ks = 0; ks < 2; ks++)
        afr[ks] = *(const bf16x8*)&bufA[wm * 64 + p * 16 + fr]
                                       [((ks * 4 + fq) ^ (fr & 7)) * 8];
      if (pre) {      // stage rounds for tile t+2: {A0,A1 | A2,A3 | B0 | B1}
        if (p == 0) {
          gl_lds16(ag,                          &sA[wave * 32 + 0][0]);
          gl_lds16(ag + (size_t)8  * lda,       &sA[wave * 32 + 8][0]);
        } else if (p == 1) {
          gl_lds16(ag + (size_t)16 * lda,       &sA[wave * 32 + 16][0]);
          gl_lds16(ag + (size_t)24 * lda,       &sA[wave * 32 + 24][0]);
        } else if (p == 2) {
          gl_lds16(bg,                          &sB[wave * 16 + 0][0]);
        } else {
          gl_lds16(bg + (size_t)8  * ldb,       &sB[wave * 16 + 8][0]);
        }
      }
      __builtin_amdgcn_s_setprio(1);
      #pragma unroll
      for (int ks = 0; ks < 2; ks++)
        #pragma unroll
        for (int nt = 0; nt < 4; nt++)
          acc[p][nt] = __builtin_amdgcn_mfma_f32_16x16x32_bf16(bfr[nt][ks], afr[ks],
                                                               acc[p][nt], 0, 0, 0);
      __builtin_amdgcn_s_setprio(0);
    }
    cb = (cb >= 2) ? 0 : cb + 1;
  }

  // transposed-C epilogue: lane holds C[gm][gn..gn+3]
  #pragma unroll
  for (int mt = 0; mt < 4; mt++) {
    const int gm = m0 + wm * 64 + mt * 16 + fr;
    #pragma unroll
    for (int nt = 0; nt < 4; nt++) {
      const int gn = n0 + wn * 64 + nt * 16 + fq * 4;
      f32x4 a = acc[mt][nt];
      if (MODE == 0) {
        ushort4 o; o.x = f2bf(a[0]); o.y = f2bf(a[1]); o.z = f2bf(a[2]); o.w = f2bf(a[3]);
        *(ushort4*)&((uint16_t*)C)[(size_t)gm * ldc + gn] = o;
      } else if (MODE == 1) {
        float4 o; o.x = a[0]; o.y = a[1]; o.z = a[2]; o.w = a[3];
        *(float4*)&((float*)C)[(size_t)gm * ldc + gn] = o;
      } else if (MODE == 2) {
        int d = gn & 127;
        if (d >= 96) {
          int s = gm & (S_ - 1);
          int i0 = (d - 96) >> 1;
          float c0 = cos_t[s * 16 + i0],     s0 = sin_t[s * 16 + i0];
          float c1 = cos_t[s * 16 + i0 + 1], s1 = sin_t[s * 16 + i0 + 1];
          float r0 = a[0] * c0 - a[1] * s0, r1 = a[0] * s0 + a[1] * c0;
          float r2 = a[2] * c1 - a[3] * s1, r3 = a[2] * s1 + a[3] * c1;
          a[0] = r0; a[1] = r1; a[2] = r2; a[3] = r3;
        }
        ushort4 o; o.x = f2bf(a[0]); o.y = f2bf(a[1]); o.z = f2bf(a[2]); o.w = f2bf(a[3]);
        *(ushort4*)&((uint16_t*)C)[(size_t)gm * ldc + gn] = o;
      } else { // MODE 3: scatter into kfin [row][h*128+d] (+RoPE on rope cols)
        int dstcol;
        if (gn < 1536) {
          int h = gn / 96;
          dstcol = h * 128 + (gn - h * 96);
        } else {
          int ln = gn - 1536;
          int h = ln >> 5, dd = ln & 31;
          int s = gm & (S_ - 1);
          int i0 = dd >> 1;
          float c0 = cos_t[s * 16 + i0],     s0 = sin_t[s * 16 + i0];
          float c1 = cos_t[s * 16 + i0 + 1], s1 = sin_t[s * 16 + i0 + 1];
          float r0 = a[0] * c0 - a[1] * s0, r1 = a[0] * s0 + a[1] * c0;
          float r2 = a[2] * c1 - a[3] * s1, r3 = a[2] * s1 + a[3] * c1;
          a[0] = r0; a[1] = r1; a[2] = r2; a[3] = r3;
          dstcol = h * 128 + 96 + dd;
        }
        ushort4 o; o.x = f2bf(a[0]); o.y = f2bf(a[1]); o.z = f2bf(a[2]); o.w = f2bf(a[3]);
        *(ushort4*)&((uint16_t*)C)[(size_t)gm * 2048 + dstcol] = o;
      }
    }
  }
}

// standalone GEMM (down-proj / out-proj): M=4096, N=2048 -> 16x16 = 256 blocks (1/CU),
// XCD-aware bijective swizzle (nwg=256, %8==0)
template<int MODE>
__global__ __launch_bounds__(512) void gemm2_k(const uint16_t* __restrict__ A,
                                               const uint16_t* __restrict__ Bt,
                                               void* __restrict__ C,
                                               int K, int lda, int ldb, int ldc) {
  __shared__ __align__(16) uint16_t lds[3 * 384][64];   // 144 KB
  const int s = (blockIdx.x & 7) * 32 + (blockIdx.x >> 3);
  gemm_body2<MODE>(A, Bt, C, s & 15, s >> 4, K, lda, ldb, ldc, nullptr, nullptr, lds);
}

// merged up-projections: q_up (RoPE), k_up (scatter+RoPE), vT — 3 x 256 blocks
__global__ __launch_bounds__(512) void up3_k(const uint16_t* __restrict__ latcat,
                                             const uint16_t* __restrict__ wquT,
                                             const uint16_t* __restrict__ wkrT,
                                             const uint16_t* __restrict__ wvT,
                                             uint16_t* __restrict__ qbuf,
                                             uint16_t* __restrict__ kfin,
                                             uint16_t* __restrict__ vTb,
                                             const float* __restrict__ cos_t,
                                             const float* __restrict__ sin_t) {
  __shared__ __align__(16) uint16_t lds[3 * 384][64];   // 144 KB
  int bid = blockIdx.x;
  if (bid < 256) {         // q_up: M=4096, N=2048, K=1536
    const int s = (bid & 7) * 32 + (bid >> 3);
    gemm_body2<2>(latcat, wquT, qbuf, s & 15, s >> 4, QR_, 2048, QR_, 2048,
                  cos_t, sin_t, lds);
  } else if (bid < 512) {  // k_up: M=4096, N=2048, K=512
    bid -= 256;
    const int s = (bid & 7) * 32 + (bid >> 3);
    gemm_body2<3>(latcat + QR_, wkrT, kfin, s & 15, s >> 4, KVR_, 2048, KVR_, 2048,
                  cos_t, sin_t, lds);
  } else {                 // vT: M=2048, N=4096, K=512
    bid -= 512;
    const int s = (bid & 7) * 32 + (bid >> 3);
    gemm_body2<0>(wvT, latcat + QR_, vTb, s & 31, s >> 5, KVR_, KVR_, 2048, BS_,
                  nullptr, nullptr, lds);
  }
}

// ---------------- flash attention v2 ----------------
// Persistent paired blocks: 256 blocks, block bid does unit bid (heavy) then
// unit 511-bid (light) -> constant 36 k-tiles/block, exact CU balance, 1 block/CU.
// Triple-buffered K/V staging, counted vmcnt(4) (tile t+1's loads stay in flight),
// ONE s_barrier per k-tile, setprio around MFMA clusters.
// Q PRE-SCALED by log2(e)/sqrt(HD); max-free exp2 softmax (unchanged math).
__global__ __launch_bounds__(512) void attn_kernel(const uint16_t* __restrict__ Q,
                                                   const uint16_t* __restrict__ Kf,
                                                   const uint16_t* __restrict__ Vt,
                                                   uint16_t* __restrict__ O) {
  __shared__ __align__(16) uint16_t Ks[3][64][128];   // 48 KB
  __shared__ __align__(16) uint16_t Vs[3][128][64];   // 48 KB
  __shared__ __align__(16) uint16_t Ps[8][16][72];    // 18 KB (wave-private P)
  const int tid = threadIdx.x, wave = tid >> 6, lane = tid & 63;
  const int fr = lane & 15, fq = lane >> 4;

  const int ksrow_lo = wave * 4 + (lane >> 4);
  const int kg_chunk0 = (lane & 15);
  const int vsrow_lo = wave * 8 + (lane >> 3);
  const int vg_chunk = (lane & 7) ^ ((lane >> 3) & 7);

  #pragma unroll
  for (int ui = 0; ui < 2; ui++) {
    const int u = ui ? (2 * NQT_ * H_ * B_ / 2 - 1 - blockIdx.x) : blockIdx.x;
    const int qt = (NQT_ - 1) - (u / (H_ * B_));
    const int hb = u % (H_ * B_);
    const int h = hb >> 1, b = hb & 1;
    const int q0 = qt * 128;
    const int qrow = q0 + wave * 16;

    bf16x8 qf[4];
    const uint16_t* qbase = Q + (size_t)(b * S_ + qrow + fr) * (H_ * HD_) + h * HD_ + fq * 8;
    #pragma unroll
    for (int s4 = 0; s4 < 4; s4++) qf[s4] = *(const bf16x8*)(qbase + s4 * 32);

    // stage whole k-tile kt into buffer sb_ (4 gl_lds per wave: 2 K + 2 V)
    auto stage = [&](int kt, int sb_) {
      #pragma unroll
      for (int i = 0; i < 2; i++) {
        int row = i * 32 + ksrow_lo;
        int g = kg_chunk0 ^ (row & 15);
        gl_lds16(Kf + (size_t)(b * S_ + kt * 64 + row) * (H_ * HD_) + h * HD_ + g * 8,
                 &Ks[sb_][i * 32 + wave * 4][0]);
      }
      #pragma unroll
      for (int i = 0; i < 2; i++) {
        int row = i * 64 + vsrow_lo;
        gl_lds16(Vt + (size_t)(h * HD_ + row) * BS_ + b * S_ + kt * 64 + vg_chunk * 8,
                 &Vs[sb_][i * 64 + wave * 8][0]);
      }
    };

    float l_s = 0.f;                       // per-lane denominator (q = qrow+fr)
    f32x4 oacc[8] = {};

    const int nkt = 2 * qt + 2;
    // protect previous unit's buffers: all waves past their last ds_reads
    __builtin_amdgcn_s_barrier();
    stage(0, 0);
    stage(1, 1);

    int cb = 0;
    for (int kt = 0; kt < nkt; kt++) {
      // tile kt landed (tile kt+1's 4 loads stay in flight); other waves' stores
      // visible after the barrier
      if (kt == nkt - 1) { asm volatile("s_waitcnt vmcnt(0)" ::: "memory"); }
      else               { asm volatile("s_waitcnt vmcnt(4)" ::: "memory"); }
      __builtin_amdgcn_s_barrier();
      asm volatile("" ::: "memory");       // no LDS reads hoist above the barrier

      const int sb = (cb >= 1) ? cb - 1 : 2;   // (cb+2)%3
      if (kt + 2 < nkt) stage(kt + 2, sb);     // prefetch overlaps full compute

      if (kt * 64 <= qrow + 15) {
        // S^T = K Q^T : tile nt covers k in [nt*16, nt*16+16)
        f32x4 sacc[4] = {};
        __builtin_amdgcn_s_setprio(1);
        #pragma unroll
        for (int ks = 0; ks < 4; ks++) {
          int pc = (ks * 4 + fq) ^ fr;
          #pragma unroll
          for (int nt = 0; nt < 4; nt++) {
            bf16x8 kfr = *(const bf16x8*)&Ks[cb][nt * 16 + fr][pc * 8];
            sacc[nt] = __builtin_amdgcn_mfma_f32_16x16x32_bf16(kfr, qf[ks], sacc[nt], 0, 0, 0);
          }
        }
        __builtin_amdgcn_s_setprio(0);
        // P = exp2(S') with causal zeroing; lane q = qrow+fr, k = kt*64+nt*16+fq*4+r
        const bool need_mask = (kt * 64 + 63 > qrow);
        const int qg = qrow + fr;
        #pragma unroll
        for (int nt = 0; nt < 4; nt++) {
          float p[4];
          #pragma unroll
          for (int r = 0; r < 4; r++) {
            float pp = __builtin_amdgcn_exp2f(sacc[nt][r]);
            if (need_mask) {
              int kg = kt * 64 + nt * 16 + fq * 4 + r;
              if (kg > qg) pp = 0.f;
            }
            l_s += pp;
            p[r] = pp;
          }
          uint2 w; w.x = pk_bf16(p[0], p[1]); w.y = pk_bf16(p[2], p[3]);
          *(uint2*)&Ps[wave][fr][nt * 16 + fq * 4] = w;
        }
        // O^T += V^T P
        __builtin_amdgcn_s_setprio(1);
        #pragma unroll
        for (int ks = 0; ks < 2; ks++) {
          bf16x8 pf = *(const bf16x8*)&Ps[wave][fr][ks * 32 + fq * 8];
          int pc = (ks * 4 + fq) ^ (fr & 7);
          #pragma unroll
          for (int d = 0; d < 8; d++) {
            bf16x8 vf = *(const bf16x8*)&Vs[cb][d * 16 + fr][pc * 8];
            oacc[d] = __builtin_amdgcn_mfma_f32_16x16x32_bf16(vf, pf, oacc[d], 0, 0, 0);
          }
        }
        __builtin_amdgcn_s_setprio(0);
      }
      cb = (cb >= 2) ? 0 : cb + 1;
    }
    // reduce denominator across the 4 fq groups
    l_s += __shfl_xor(l_s, 16);
    l_s += __shfl_xor(l_s, 32);
    const float inv_l = 1.0f / l_s;
    // O^T C-layout: lane holds q=fr, d = dt*16 + fq*4 + r
    const int gm = b * S_ + qrow + fr;
    #pragma unroll
    for (int dt = 0; dt < 8; dt++) {
      ushort4 o;
      o.x = f2bf(oacc[dt][0] * inv_l); o.y = f2bf(oacc[dt][1] * inv_l);
      o.z = f2bf(oacc[dt][2] * inv_l); o.w = f2bf(oacc[dt][3] * inv_l);
      *(ushort4*)&O[(size_t)gm * (H_ * HD_) + h * HD_ + dt * 16 + fq * 4] = o;
    }
  }
}

extern "C" void kernel_launch(void* const* d_in, const int* in_sizes, int n_in,
                              void* d_out, int out_size, void* d_ws, size_t ws_size,
                              hipStream_t stream) {
  const float* x        = (const float*)d_in[0];
  const float* fcos     = (const float*)d_in[1];
  const float* fsin     = (const float*)d_in[2];
  const float* wq_down  = (const float*)d_in[3];
  const float* wq_up    = (const float*)d_in[4];
  const float* wkv_down = (const float*)d_in[5];
  const float* w_nope   = (const float*)d_in[6];
  const float* w_rope   = (const float*)d_in[7];
  const float* w_val    = (const float*)d_in[8];
  const float* wo       = (const float*)d_in[9];
  float* out = (float*)d_out;

  char* ws = (char*)d_ws;
  size_t off = 0;
  auto alloc = [&](size_t elems) {
    uint16_t* p = (uint16_t*)(ws + off);
    off += elems * 2; off = (off + 255) & ~(size_t)255;
    return p;
  };
  uint16_t* xb     = alloc((size_t)BS_ * DIM_);
  uint16_t* wdT    = alloc((size_t)(QR_ + KVR_) * DIM_);     // [wq_downT ; wkv_downT]
  uint16_t* wquT   = alloc((size_t)(H_ * HD_) * QR_);        // pre-scaled by log2e/sqrt(HD)
  uint16_t* wkrT   = alloc((size_t)(H_ * NOPE_ + H_ * ROPE_) * KVR_); // [w_nopeT ; w_ropeT]
  uint16_t* wvT    = alloc((size_t)(H_ * HD_) * KVR_);
  uint16_t* woT    = alloc((size_t)DIM_ * (H_ * HD_));
  uint16_t* latcat = alloc((size_t)BS_ * (QR_ + KVR_));      // [qlat | kv]
  uint16_t* qbuf   = alloc((size_t)BS_ * (H_ * HD_));
  uint16_t* kfin   = alloc((size_t)BS_ * (H_ * HD_));
  uint16_t* vTb    = alloc((size_t)(H_ * HD_) * BS_);
  uint16_t* aout   = alloc((size_t)BS_ * (H_ * HD_));

  const float qscale = 0.12751743f; // log2(e)/sqrt(128) — exp2-based softmax

  prep_k<<<dim3(PREP_BLKS), 256, 0, stream>>>(x, wq_down, wq_up, wkv_down, w_nope,
      w_rope, w_val, wo, xb, wdT, wquT, wkrT, wvT, woT, qscale);

  // fused down-projection: latcat = xb @ [wq_down | wkv_down]   (256 blocks, 1/CU)
  gemm2_k<0><<<dim3(256), 512, 0, stream>>>(xb, wdT, latcat, DIM_, DIM_, DIM_, 2048);
  // merged up-projections (q_up + RoPE, k_up + scatter/RoPE, vT) — 768 blocks
  up3_k<<<dim3(768), 512, 0, stream>>>(latcat, wquT, wkrT, wvT, qbuf, kfin, vTb,
      fcos, fsin);

  // persistent paired attention: 256 blocks, each does units (bid, 511-bid)
  attn_kernel<<<dim3(NQT_ * H_ * B_ / 2), 512, 0, stream>>>(qbuf, kfin, vTb, aout);
  gemm2_k<1><<<dim3(256), 512, 0, stream>>>(aout, woT, out, DIM_, DIM_, DIM_, DIM_);
}

// Round 4
// 319.772 us; speedup vs baseline: 1.0720x; 1.0720x over previous
//
#include <hip/hip_runtime.h>
#include <hip/hip_bf16.h>
#include <stdint.h>

#define B_    2
#define S_    2048
#define DIM_  2048
#define H_    16
#define NOPE_ 96
#define ROPE_ 32
#define HD_   128
#define KVR_  512
#define QR_   1536
#define BS_   (B_*S_)   // 4096
#define NQT_  (S_/128)  // 16 q-tiles per (b,h)

typedef __bf16 bf16_t;
typedef bf16_t bf16x8 __attribute__((ext_vector_type(8)));
typedef bf16_t bf16x4 __attribute__((ext_vector_type(4)));
typedef float  f32x4  __attribute__((ext_vector_type(4)));

__device__ __forceinline__ uint16_t f2bf(float f) {
  union { float f; uint32_t u; } v; v.f = f;
  uint32_t r = (v.u + 0x7fffu + ((v.u >> 16) & 1u)) >> 16;
  return (uint16_t)r;
}

// async global->LDS, 16B per lane; LDS dest is wave-uniform base + lane*16
__device__ __forceinline__ void gl_lds16(const void* g, void* l) {
  __builtin_amdgcn_global_load_lds(
      (const __attribute__((address_space(1))) uint32_t*)g,
      (__attribute__((address_space(3))) uint32_t*)l, 16, 0, 0);
}

// ---------------- prep megakernel: cast x + all weight transposes ----------------
__device__ __forceinline__ void transpose_tile(const float* __restrict__ W,
                                               uint16_t* __restrict__ Wt,
                                               int K, int N, float scale, int lbid,
                                               float (*tile)[65]) {
  const int nb = N / 64;
  const int n0 = (lbid % nb) * 64, k0 = (lbid / nb) * 64;
  const int tid = threadIdx.x;
  #pragma unroll
  for (int i = 0; i < 4; i++) {
    int p = i * 256 + tid;
    int r = p >> 4, c4 = (p & 15) * 4;
    float4 v = *(const float4*)&W[(size_t)(k0 + r) * N + n0 + c4];
    tile[r][c4 + 0] = v.x; tile[r][c4 + 1] = v.y; tile[r][c4 + 2] = v.z; tile[r][c4 + 3] = v.w;
  }
  __syncthreads();
  #pragma unroll
  for (int i = 0; i < 4; i++) {
    int p = i * 256 + tid;
    int rn = p >> 4, c4 = (p & 15) * 4;
    ushort4 o;
    o.x = f2bf(tile[c4 + 0][rn] * scale); o.y = f2bf(tile[c4 + 1][rn] * scale);
    o.z = f2bf(tile[c4 + 2][rn] * scale); o.w = f2bf(tile[c4 + 3][rn] * scale);
    *(ushort4*)&Wt[(size_t)(n0 + rn) * K + k0 + c4] = o;
  }
}

#define CAST_BLKS 2048   // 8.4M elems / 4096
__global__ __launch_bounds__(256) void prep_k(
    const float* __restrict__ x,
    const float* __restrict__ wqd, const float* __restrict__ wqu,
    const float* __restrict__ wkvd, const float* __restrict__ wn,
    const float* __restrict__ wr, const float* __restrict__ wv,
    const float* __restrict__ wo,
    uint16_t* __restrict__ xb, uint16_t* __restrict__ wdT,
    uint16_t* __restrict__ wquT, uint16_t* __restrict__ wkrT,
    uint16_t* __restrict__ wvT, uint16_t* __restrict__ woT, float qscale) {
  __shared__ __align__(16) float tile[64][65];
  int bid = blockIdx.x;
  const int tid = threadIdx.x;
  if (bid < CAST_BLKS) {
    #pragma unroll
    for (int p = 0; p < 4; p++) {
      int i = bid * 4096 + p * 1024 + tid * 4;
      float4 v = *(const float4*)&x[i];
      ushort4 o; o.x = f2bf(v.x); o.y = f2bf(v.y); o.z = f2bf(v.z); o.w = f2bf(v.w);
      *(ushort4*)&xb[i] = o;
    }
    return;
  }
  bid -= CAST_BLKS;
  if (bid < 768)               transpose_tile(wqd,  wdT,                        2048, 1536, 1.f,    bid, tile);
  else if ((bid -= 768) < 256) transpose_tile(wkvd, wdT + (size_t)QR_ * DIM_,   2048,  512, 1.f,    bid, tile);
  else if ((bid -= 256) < 768) transpose_tile(wqu,  wquT,                       1536, 2048, qscale, bid, tile);
  else if ((bid -= 768) < 192) transpose_tile(wn,   wkrT,                        512, 1536, 1.f,    bid, tile);
  else if ((bid -= 192) < 64)  transpose_tile(wr,   wkrT + (size_t)1536 * 512,   512,  512, 1.f,    bid, tile);
  else if ((bid -= 64) < 256)  transpose_tile(wv,   wvT,                         512, 2048, 1.f,    bid, tile);
  else                         transpose_tile(wo,   woT, 2048, 2048, 1.f, bid - 256, tile);
}
#define PREP_BLKS (CAST_BLKS + 768 + 256 + 768 + 192 + 64 + 256 + 1024)

// ---------------- GEMM v2: C(MxN) = A(MxK,bf16) * Bt(NxK,bf16)^T ----------------
// 256x128 tile, BK=64, 8 waves (4M x 2N, 64x64 per wave), triple-buffered LDS (144 KB),
// counted vmcnt(6) pipeline (never drains in main loop), ONE raw s_barrier per K-tile,
// s_setprio around MFMA clusters.
// MODE 0: bf16; 1: f32; 2: q_up + RoPE (d>=96); 3: k_up + nope/rope scatter.
template<int MODE>
__device__ __forceinline__ void gemm_body2(const uint16_t* __restrict__ A,
                                           const uint16_t* __restrict__ Bt,
                                           void* __restrict__ C,
                                           int bx, int by, int K,
                                           int lda, int ldb, int ldc,
                                           const float* __restrict__ cos_t,
                                           const float* __restrict__ sin_t,
                                           uint16_t (*lds)[64]) {
  const int tid = threadIdx.x;
  const int wave = tid >> 6, lane = tid & 63;
  const int wm = wave & 3, wn = wave >> 2;      // 4M x 2N
  const int m0 = by * 256, n0 = bx * 128;
  const int fr = lane & 15, fq = lane >> 4;

  const int srow = lane >> 3;                   // 0..7
  const int sch  = (lane & 7) ^ (srow & 7);     // pre-swizzled k-chunk

  // per-lane global staging bases (swizzled chunk baked in)
  const uint16_t* Ag = A  + (size_t)(m0 + wave * 32 + srow) * lda + sch * 8;
  const uint16_t* Bg = Bt + (size_t)(n0 + wave * 16 + srow) * ldb + sch * 8;
  const int NT = K >> 6;

  // stage whole K-tile t into buffer b (6 gl_lds per wave: 4 A rounds + 2 B rounds)
  auto stage_all = [&](int t, int b) {
    uint16_t (*bufA)[64] = lds + b * 384;
    uint16_t (*bufB)[64] = lds + b * 384 + 256;
    const uint16_t* ag = Ag + (size_t)t * 64;
    const uint16_t* bg = Bg + (size_t)t * 64;
    #pragma unroll
    for (int i = 0; i < 4; i++)
      gl_lds16(ag + (size_t)(i * 8) * lda, &bufA[wave * 32 + i * 8][0]);
    #pragma unroll
    for (int i = 0; i < 2; i++)
      gl_lds16(bg + (size_t)(i * 8) * ldb, &bufB[wave * 16 + i * 8][0]);
  };

  f32x4 acc[4][4] = {};
  stage_all(0, 0);   // prologue: tiles 0 and 1 in flight (12 loads/wave)
  stage_all(1, 1);

  int cb = 0;        // compute buffer = t % 3
  for (int t = 0; t < NT; ++t) {
    const bool pre = (t + 2 < NT);
    const int sb = (cb >= 1) ? cb - 1 : 2;      // (cb+2)%3 — stage buffer
    uint16_t (*bufA)[64] = lds + cb * 384;
    uint16_t (*bufB)[64] = lds + cb * 384 + 256;
    uint16_t (*sA)[64]   = lds + sb * 384;
    uint16_t (*sB)[64]   = lds + sb * 384 + 256;
    const uint16_t* ag = Ag + (size_t)(t + 2) * 64;
    const uint16_t* bg = Bg + (size_t)(t + 2) * 64;

    // tile t landed (6 newest = tile t+1 stay in flight); all waves' stores visible
    if (t == NT - 1) { asm volatile("s_waitcnt vmcnt(0)" ::: "memory"); }
    else             { asm volatile("s_waitcnt vmcnt(6)" ::: "memory"); }
    __builtin_amdgcn_s_barrier();
    asm volatile("" ::: "memory");   // fence: no LDS reads hoist above the barrier

    // B fragments for the whole tile (shared across the 4 m-phases)
    bf16x8 bfr[4][2];
    #pragma unroll
    for (int nt = 0; nt < 4; nt++)
      #pragma unroll
      for (int ks = 0; ks < 2; ks++)
        bfr[nt][ks] = *(const bf16x8*)&bufB[wn * 64 + nt * 16 + fr]
                                          [((ks * 4 + fq) ^ (fr & 7)) * 8];

    #pragma unroll
    for (int p = 0; p < 4; p++) {
      bf16x8 afr[2];
      #pragma unroll
      for (int ks = 0; ks < 2; ks++)
        afr[ks] = *(const bf16x8*)&bufA[wm * 64 + p * 16 + fr]
                                       [((ks * 4 + fq) ^ (fr & 7)) * 8];
      if (pre) {      // stage rounds for tile t+2: {A0,A1 | A2,A3 | B0 | B1}
        if (p == 0) {
          gl_lds16(ag,                          &sA[wave * 32 + 0][0]);
          gl_lds16(ag + (size_t)8  * lda,       &sA[wave * 32 + 8][0]);
        } else if (p == 1) {
          gl_lds16(ag + (size_t)16 * lda,       &sA[wave * 32 + 16][0]);
          gl_lds16(ag + (size_t)24 * lda,       &sA[wave * 32 + 24][0]);
        } else if (p == 2) {
          gl_lds16(bg,                          &sB[wave * 16 + 0][0]);
        } else {
          gl_lds16(bg + (size_t)8  * ldb,       &sB[wave * 16 + 8][0]);
        }
      }
      __builtin_amdgcn_s_setprio(1);
      #pragma unroll
      for (int ks = 0; ks < 2; ks++)
        #pragma unroll
        for (int nt = 0; nt < 4; nt++)
          acc[p][nt] = __builtin_amdgcn_mfma_f32_16x16x32_bf16(bfr[nt][ks], afr[ks],
                                                               acc[p][nt], 0, 0, 0);
      __builtin_amdgcn_s_setprio(0);
    }
    cb = (cb >= 2) ? 0 : cb + 1;
  }

  // transposed-C epilogue: lane holds C[gm][gn..gn+3]
  #pragma unroll
  for (int mt = 0; mt < 4; mt++) {
    const int gm = m0 + wm * 64 + mt * 16 + fr;
    #pragma unroll
    for (int nt = 0; nt < 4; nt++) {
      const int gn = n0 + wn * 64 + nt * 16 + fq * 4;
      f32x4 a = acc[mt][nt];
      if (MODE == 0) {
        ushort4 o; o.x = f2bf(a[0]); o.y = f2bf(a[1]); o.z = f2bf(a[2]); o.w = f2bf(a[3]);
        *(ushort4*)&((uint16_t*)C)[(size_t)gm * ldc + gn] = o;
      } else if (MODE == 1) {
        float4 o; o.x = a[0]; o.y = a[1]; o.z = a[2]; o.w = a[3];
        *(float4*)&((float*)C)[(size_t)gm * ldc + gn] = o;
      } else if (MODE == 2) {
        int d = gn & 127;
        if (d >= 96) {
          int s = gm & (S_ - 1);
          int i0 = (d - 96) >> 1;
          float c0 = cos_t[s * 16 + i0],     s0 = sin_t[s * 16 + i0];
          float c1 = cos_t[s * 16 + i0 + 1], s1 = sin_t[s * 16 + i0 + 1];
          float r0 = a[0] * c0 - a[1] * s0, r1 = a[0] * s0 + a[1] * c0;
          float r2 = a[2] * c1 - a[3] * s1, r3 = a[2] * s1 + a[3] * c1;
          a[0] = r0; a[1] = r1; a[2] = r2; a[3] = r3;
        }
        ushort4 o; o.x = f2bf(a[0]); o.y = f2bf(a[1]); o.z = f2bf(a[2]); o.w = f2bf(a[3]);
        *(ushort4*)&((uint16_t*)C)[(size_t)gm * ldc + gn] = o;
      } else { // MODE 3: scatter into kfin [row][h*128+d] (+RoPE on rope cols)
        int dstcol;
        if (gn < 1536) {
          int h = gn / 96;
          dstcol = h * 128 + (gn - h * 96);
        } else {
          int ln = gn - 1536;
          int h = ln >> 5, dd = ln & 31;
          int s = gm & (S_ - 1);
          int i0 = dd >> 1;
          float c0 = cos_t[s * 16 + i0],     s0 = sin_t[s * 16 + i0];
          float c1 = cos_t[s * 16 + i0 + 1], s1 = sin_t[s * 16 + i0 + 1];
          float r0 = a[0] * c0 - a[1] * s0, r1 = a[0] * s0 + a[1] * c0;
          float r2 = a[2] * c1 - a[3] * s1, r3 = a[2] * s1 + a[3] * c1;
          a[0] = r0; a[1] = r1; a[2] = r2; a[3] = r3;
          dstcol = h * 128 + 96 + dd;
        }
        ushort4 o; o.x = f2bf(a[0]); o.y = f2bf(a[1]); o.z = f2bf(a[2]); o.w = f2bf(a[3]);
        *(ushort4*)&((uint16_t*)C)[(size_t)gm * 2048 + dstcol] = o;
      }
    }
  }
}

// standalone GEMM (down-proj / out-proj): M=4096, N=2048 -> 16x16 = 256 blocks (1/CU),
// XCD-aware bijective swizzle (nwg=256, %8==0)
template<int MODE>
__global__ __launch_bounds__(512) void gemm2_k(const uint16_t* __restrict__ A,
                                               const uint16_t* __restrict__ Bt,
                                               void* __restrict__ C,
                                               int K, int lda, int ldb, int ldc) {
  __shared__ __align__(16) uint16_t lds[3 * 384][64];   // 144 KB
  const int s = (blockIdx.x & 7) * 32 + (blockIdx.x >> 3);
  gemm_body2<MODE>(A, Bt, C, s & 15, s >> 4, K, lda, ldb, ldc, nullptr, nullptr, lds);
}

// merged up-projections: q_up (RoPE), k_up (scatter+RoPE), vT — 3 x 256 blocks
__global__ __launch_bounds__(512) void up3_k(const uint16_t* __restrict__ latcat,
                                             const uint16_t* __restrict__ wquT,
                                             const uint16_t* __restrict__ wkrT,
                                             const uint16_t* __restrict__ wvT,
                                             uint16_t* __restrict__ qbuf,
                                             uint16_t* __restrict__ kfin,
                                             uint16_t* __restrict__ vTb,
                                             const float* __restrict__ cos_t,
                                             const float* __restrict__ sin_t) {
  __shared__ __align__(16) uint16_t lds[3 * 384][64];   // 144 KB
  int bid = blockIdx.x;
  if (bid < 256) {         // q_up: M=4096, N=2048, K=1536
    const int s = (bid & 7) * 32 + (bid >> 3);
    gemm_body2<2>(latcat, wquT, qbuf, s & 15, s >> 4, QR_, 2048, QR_, 2048,
                  cos_t, sin_t, lds);
  } else if (bid < 512) {  // k_up: M=4096, N=2048, K=512
    bid -= 256;
    const int s = (bid & 7) * 32 + (bid >> 3);
    gemm_body2<3>(latcat + QR_, wkrT, kfin, s & 15, s >> 4, KVR_, 2048, KVR_, 2048,
                  cos_t, sin_t, lds);
  } else {                 // vT: M=2048, N=4096, K=512
    bid -= 512;
    const int s = (bid & 7) * 32 + (bid >> 3);
    gemm_body2<0>(wvT, latcat + QR_, vTb, s & 31, s >> 5, KVR_, KVR_, 2048, BS_,
                  nullptr, nullptr, lds);
  }
}

// ---------------- flash attention v3 ----------------
// 512 blocks (one unit each, 2 blocks/CU for inter-block MFMA/VALU de-phasing),
// double-buffered K/V with counted vmcnt(4) (next tile's loads stay in flight;
// no vmcnt(0) drain except last tile), 2 barriers/tile, stage(t+2) after the
// post-compute barrier (full tile of compute hides L2 latency).
// LDS = 32+32+16 = 80 KB exactly -> 2 blocks/CU.
// Ps: [8][16][64] with XOR-16B swizzle within each row (replaces pad-72; same-key
// bijection on write(b64) and read(b128) -> uniform bank distribution).
// Block remap: bid<256 -> u=bid (heavy, qt 15..8); else u reversed-light so blocks
// c and 256+c (same CU under round-robin) sum to constant 36 k-tiles.
// Q PRE-SCALED by log2(e)/sqrt(HD); max-free exp2 softmax (unchanged math).
__global__ __launch_bounds__(512) void attn_kernel(const uint16_t* __restrict__ Q,
                                                   const uint16_t* __restrict__ Kf,
                                                   const uint16_t* __restrict__ Vt,
                                                   uint16_t* __restrict__ O) {
  __shared__ __align__(16) uint16_t Ks[2][64][128];   // 32 KB
  __shared__ __align__(16) uint16_t Vs[2][128][64];   // 32 KB
  __shared__ __align__(16) uint16_t Ps[8][16][64];    // 16 KB (XOR-swizzled rows)
  int u;
  if (blockIdx.x < 256) { u = blockIdx.x; }
  else { int c = blockIdx.x - 256; u = (15 - (c >> 5)) * 32 + (c & 31); }
  const int qt = (NQT_ - 1) - (u >> 5);
  const int hb = u & 31;
  const int h = hb >> 1, b = hb & 1;
  const int tid = threadIdx.x, wave = tid >> 6, lane = tid & 63;
  const int fr = lane & 15, fq = lane >> 4;
  const int q0 = qt * 128;
  const int qrow = q0 + wave * 16;

  bf16x8 qf[4];
  const uint16_t* qbase = Q + (size_t)(b * S_ + qrow + fr) * (H_ * HD_) + h * HD_ + fq * 8;
  #pragma unroll
  for (int s4 = 0; s4 < 4; s4++) qf[s4] = *(const bf16x8*)(qbase + s4 * 32);
  asm volatile("s_waitcnt vmcnt(0)" ::: "memory");   // exact vmcnt bookkeeping below

  const int ksrow_lo = wave * 4 + (lane >> 4);
  const int kg_chunk0 = (lane & 15);
  const int vsrow_lo = wave * 8 + (lane >> 3);
  const int vg_chunk = (lane & 7) ^ ((lane >> 3) & 7);

  // stage whole k-tile kt into buffer sb_ (4 gl_lds per wave: 2 K + 2 V)
  auto stage = [&](int kt, int sb_) {
    #pragma unroll
    for (int i = 0; i < 2; i++) {
      int row = i * 32 + ksrow_lo;
      int g = kg_chunk0 ^ (row & 15);
      gl_lds16(Kf + (size_t)(b * S_ + kt * 64 + row) * (H_ * HD_) + h * HD_ + g * 8,
               &Ks[sb_][i * 32 + wave * 4][0]);
    }
    #pragma unroll
    for (int i = 0; i < 2; i++) {
      int row = i * 64 + vsrow_lo;
      gl_lds16(Vt + (size_t)(h * HD_ + row) * BS_ + b * S_ + kt * 64 + vg_chunk * 8,
               &Vs[sb_][i * 64 + wave * 8][0]);
    }
  };

  float l_s = 0.f;                       // per-lane denominator (q = qrow+fr)
  f32x4 oacc[8] = {};
  uint8_t* psrow = (uint8_t*)&Ps[wave][fr][0];
  const int pskey = (fr & 7) << 4;       // 16B XOR key, same on write and read

  const int nkt = 2 * qt + 2;
  stage(0, 0);
  stage(1, 1);

  for (int kt = 0; kt < nkt; kt++) {
    // stage(kt) landed; stage(kt+1)'s 4 loads stay in flight
    if (kt == nkt - 1) { asm volatile("s_waitcnt vmcnt(0)" ::: "memory"); }
    else               { asm volatile("s_waitcnt vmcnt(4)" ::: "memory"); }
    __builtin_amdgcn_s_barrier();
    asm volatile("" ::: "memory");       // no LDS reads hoist above the barrier
    const int cb = kt & 1;

    if (kt * 64 <= qrow + 15) {
      // S^T = K Q^T : tile nt covers k in [nt*16, nt*16+16)
      f32x4 sacc[4] = {};
      __builtin_amdgcn_s_setprio(1);
      #pragma unroll
      for (int ks = 0; ks < 4; ks++) {
        int pc = (ks * 4 + fq) ^ fr;
        #pragma unroll
        for (int nt = 0; nt < 4; nt++) {
          bf16x8 kfr = *(const bf16x8*)&Ks[cb][nt * 16 + fr][pc * 8];
          sacc[nt] = __builtin_amdgcn_mfma_f32_16x16x32_bf16(kfr, qf[ks], sacc[nt], 0, 0, 0);
        }
      }
      __builtin_amdgcn_s_setprio(0);
      // P = exp2(S') with causal zeroing; lane q = qrow+fr, k = kt*64+nt*16+fq*4+r
      const bool need_mask = (kt * 64 + 63 > qrow);
      const int qg = qrow + fr;
      #pragma unroll
      for (int nt = 0; nt < 4; nt++) {
        float p[4];
        #pragma unroll
        for (int r = 0; r < 4; r++) {
          float pp = __builtin_amdgcn_exp2f(sacc[nt][r]);
          if (need_mask) {
            int kg = kt * 64 + nt * 16 + fq * 4 + r;
            if (kg > qg) pp = 0.f;
          }
          l_s += pp;
          p[r] = pp;
        }
        // native casts -> v_cvt_pk_bf16_f32 (RNE, bit-identical to manual pack)
        bf16x4 w; w[0] = (bf16_t)p[0]; w[1] = (bf16_t)p[1];
        w[2] = (bf16_t)p[2]; w[3] = (bf16_t)p[3];
        *(bf16x4*)(psrow + ((nt * 32 + fq * 8) ^ pskey)) = w;
      }
      // O^T += V^T P
      __builtin_amdgcn_s_setprio(1);
      #pragma unroll
      for (int ks = 0; ks < 2; ks++) {
        bf16x8 pf = *(const bf16x8*)(psrow + ((ks * 64 + fq * 16) ^ pskey));
        int pc = (ks * 4 + fq) ^ (fr & 7);
        #pragma unroll
        for (int d = 0; d < 8; d++) {
          bf16x8 vf = *(const bf16x8*)&Vs[cb][d * 16 + fr][pc * 8];
          oacc[d] = __builtin_amdgcn_mfma_f32_16x16x32_bf16(vf, pf, oacc[d], 0, 0, 0);
        }
      }
      __builtin_amdgcn_s_setprio(0);
    }
    __builtin_amdgcn_s_barrier();        // all waves done reading buf cb
    if (kt + 2 < nkt) stage(kt + 2, cb); // refill the just-freed buffer
  }
  // reduce denominator across the 4 fq groups
  l_s += __shfl_xor(l_s, 16);
  l_s += __shfl_xor(l_s, 32);
  const float inv_l = 1.0f / l_s;
  // O^T C-layout: lane holds q=fr, d = dt*16 + fq*4 + r
  const int gm = b * S_ + qrow + fr;
  #pragma unroll
  for (int dt = 0; dt < 8; dt++) {
    ushort4 o;
    o.x = f2bf(oacc[dt][0] * inv_l); o.y = f2bf(oacc[dt][1] * inv_l);
    o.z = f2bf(oacc[dt][2] * inv_l); o.w = f2bf(oacc[dt][3] * inv_l);
    *(ushort4*)&O[(size_t)gm * (H_ * HD_) + h * HD_ + dt * 16 + fq * 4] = o;
  }
}

extern "C" void kernel_launch(void* const* d_in, const int* in_sizes, int n_in,
                              void* d_out, int out_size, void* d_ws, size_t ws_size,
                              hipStream_t stream) {
  const float* x        = (const float*)d_in[0];
  const float* fcos     = (const float*)d_in[1];
  const float* fsin     = (const float*)d_in[2];
  const float* wq_down  = (const float*)d_in[3];
  const float* wq_up    = (const float*)d_in[4];
  const float* wkv_down = (const float*)d_in[5];
  const float* w_nope   = (const float*)d_in[6];
  const float* w_rope   = (const float*)d_in[7];
  const float* w_val    = (const float*)d_in[8];
  const float* wo       = (const float*)d_in[9];
  float* out = (float*)d_out;

  char* ws = (char*)d_ws;
  size_t off = 0;
  auto alloc = [&](size_t elems) {
    uint16_t* p = (uint16_t*)(ws + off);
    off += elems * 2; off = (off + 255) & ~(size_t)255;
    return p;
  };
  uint16_t* xb     = alloc((size_t)BS_ * DIM_);
  uint16_t* wdT    = alloc((size_t)(QR_ + KVR_) * DIM_);     // [wq_downT ; wkv_downT]
  uint16_t* wquT   = alloc((size_t)(H_ * HD_) * QR_);        // pre-scaled by log2e/sqrt(HD)
  uint16_t* wkrT   = alloc((size_t)(H_ * NOPE_ + H_ * ROPE_) * KVR_); // [w_nopeT ; w_ropeT]
  uint16_t* wvT    = alloc((size_t)(H_ * HD_) * KVR_);
  uint16_t* woT    = alloc((size_t)DIM_ * (H_ * HD_));
  uint16_t* latcat = alloc((size_t)BS_ * (QR_ + KVR_));      // [qlat | kv]
  uint16_t* qbuf   = alloc((size_t)BS_ * (H_ * HD_));
  uint16_t* kfin   = alloc((size_t)BS_ * (H_ * HD_));
  uint16_t* vTb    = alloc((size_t)(H_ * HD_) * BS_);
  uint16_t* aout   = alloc((size_t)BS_ * (H_ * HD_));

  const float qscale = 0.12751743f; // log2(e)/sqrt(128) — exp2-based softmax

  prep_k<<<dim3(PREP_BLKS), 256, 0, stream>>>(x, wq_down, wq_up, wkv_down, w_nope,
      w_rope, w_val, wo, xb, wdT, wquT, wkrT, wvT, woT, qscale);

  // fused down-projection: latcat = xb @ [wq_down | wkv_down]   (256 blocks, 1/CU)
  gemm2_k<0><<<dim3(256), 512, 0, stream>>>(xb, wdT, latcat, DIM_, DIM_, DIM_, 2048);
  // merged up-projections (q_up + RoPE, k_up + scatter/RoPE, vT) — 768 blocks
  up3_k<<<dim3(768), 512, 0, stream>>>(latcat, wquT, wkrT, wvT, qbuf, kfin, vTb,
      fcos, fsin);

  // attention: 512 blocks (2/CU), CU-paired heavy+light remap
  attn_kernel<<<dim3(NQT_ * H_ * B_), 512, 0, stream>>>(qbuf, kfin, vTb, aout);
  gemm2_k<1><<<dim3(256), 512, 0, stream>>>(aout, woT, out, DIM_, DIM_, DIM_, DIM_);
}